// Round 4
// baseline (341.842 us; speedup 1.0000x reference)
//
#include <hip/hip_runtime.h>

#define B_ROWS   16384
#define K_NB     64
#define D_DIM    256
#define TWO_D    512
#define R_BLK    8          // rows per block
#define THREADS  256
#define NSLOT    8          // staging slots (1 KB each) per wave

// async global->LDS DMA: data bypasses VGPRs; LDS dest = slot base + lane*16
#define GLD16(g, l)                                                          \
    __builtin_amdgcn_global_load_lds(                                        \
        (const __attribute__((address_space(1))) void*)(g),                  \
        (__attribute__((address_space(3))) void*)(l), 16, 0, 0)

#define WAIT_VMCNT_0() asm volatile("s_waitcnt vmcnt(0)" ::: "memory")
#define WAIT_VMCNT_4() asm volatile("s_waitcnt vmcnt(4)" ::: "memory")

__global__ __launch_bounds__(THREADS)
void easyrec_fused(const int* __restrict__ nodes_u,
                   const int* __restrict__ nodes_v,
                   const int* __restrict__ neighbors,
                   const int* __restrict__ neighbor_counts,
                   const float* __restrict__ u2e,
                   const float* __restrict__ v2e,
                   const float* __restrict__ W,      // [D, 2D] row-major
                   const float* __restrict__ bias,   // [D]
                   float* __restrict__ out)          // [B]
{
    __shared__ __align__(16) int   nbr_lds[R_BLK * K_NB];        // 2 KB
    __shared__ __align__(16) float cat_lds[R_BLK][TWO_D];        // 16 KB
    __shared__ __align__(16) float stage[4][NSLOT * D_DIM];      // 32 KB: 8 KB per wave
    __shared__ float red_lds[R_BLK * 4];
    __shared__ float selfdot_lds[R_BLK];
    __shared__ float bdot_lds[R_BLK];

    const int t    = threadIdx.x;
    const int wave = t >> 6;
    const int lane = t & 63;
    const int row0 = blockIdx.x * R_BLK;
    const int col  = 4 * lane;
    float* const st = &stage[wave][0];

    // ---- stage neighbor indices for the 8 rows (512 ints, coalesced) ----
    nbr_lds[t]           = neighbors[(size_t)row0 * K_NB + t];
    nbr_lds[t + THREADS] = neighbors[(size_t)row0 * K_NB + t + THREADS];
    __syncthreads();

    // ---- prologue: self/v/bias scalars (regs dead before the gather loop) ----
    const int r0 = wave, r1 = wave + 4;
    const int cnt0 = __builtin_amdgcn_readfirstlane(neighbor_counts[row0 + r0]);
    const int cnt1 = __builtin_amdgcn_readfirstlane(neighbor_counts[row0 + r1]);
    {
        const float4 b4 = *(const float4*)(bias + col);
        #pragma unroll
        for (int rr = 0; rr < 2; ++rr) {
            const int r  = (rr == 0) ? r0 : r1;
            const int nu = __builtin_amdgcn_readfirstlane(nodes_u[row0 + r]);
            const int nv = __builtin_amdgcn_readfirstlane(nodes_v[row0 + r]);
            const float4 self4 = *(const float4*)(u2e + (size_t)nu * D_DIM + col);
            const float4 v4    = *(const float4*)(v2e + (size_t)nv * D_DIM + col);
            *(float4*)(&cat_lds[r][col]) = self4;
            float sv = self4.x * v4.x + self4.y * v4.y + self4.z * v4.z + self4.w * v4.w;
            float bv = b4.x * v4.x + b4.y * v4.y + b4.z * v4.z + b4.w * v4.w;
            #pragma unroll
            for (int off = 32; off > 0; off >>= 1) {
                sv += __shfl_xor(sv, off, 64);
                bv += __shfl_xor(bv, off, 64);
            }
            if (lane == 0) { selfdot_lds[r] = sv; bdot_lds[r] = bv; }
        }
    }

    // ---- phase 1: async-DMA gather, 4-row groups double-buffered in LDS ----
    // neighbors[] entries are always valid; over-read past cnt, mask the accumulate.
    #pragma unroll
    for (int rr = 0; rr < 2; ++rr) {
        const int r   = (rr == 0) ? r0 : r1;
        const int cnt = (rr == 0) ? cnt0 : cnt1;
        float4 acc = make_float4(0.f, 0.f, 0.f, 0.f);

        if (cnt > 0) {
            const int base = r * K_NB;
            const int G = (cnt + 3) >> 2;          // 4-row groups (indices past cnt are valid)

            // make vmcnt accounting exact before the pipeline starts
            WAIT_VMCNT_0();

            // issue group 0 -> slots 0..3
            {
                const int4 ia = *(const int4*)&nbr_lds[base];
                GLD16(u2e + (size_t)ia.x * D_DIM + col, st + 0 * D_DIM);
                GLD16(u2e + (size_t)ia.y * D_DIM + col, st + 1 * D_DIM);
                GLD16(u2e + (size_t)ia.z * D_DIM + col, st + 2 * D_DIM);
                GLD16(u2e + (size_t)ia.w * D_DIM + col, st + 3 * D_DIM);
            }
            for (int g = 0; g < G; ++g) {
                const int cur = (g & 1) * 4;
                if (g + 1 < G) {
                    const int nxt = ((g + 1) & 1) * 4;
                    const int4 ia = *(const int4*)&nbr_lds[base + 4 * (g + 1)];
                    GLD16(u2e + (size_t)ia.x * D_DIM + col, st + (nxt + 0) * D_DIM);
                    GLD16(u2e + (size_t)ia.y * D_DIM + col, st + (nxt + 1) * D_DIM);
                    GLD16(u2e + (size_t)ia.z * D_DIM + col, st + (nxt + 2) * D_DIM);
                    GLD16(u2e + (size_t)ia.w * D_DIM + col, st + (nxt + 3) * D_DIM);
                    WAIT_VMCNT_4();                 // group g landed; g+1 still in flight
                } else {
                    WAIT_VMCNT_0();                 // last group: drain
                }
                const float4 n0 = *(const float4*)(st + (cur + 0) * D_DIM + col);
                const float4 n1 = *(const float4*)(st + (cur + 1) * D_DIM + col);
                const float4 n2 = *(const float4*)(st + (cur + 2) * D_DIM + col);
                const float4 n3 = *(const float4*)(st + (cur + 3) * D_DIM + col);
                if (4 * g + 4 <= cnt) {
                    acc.x += n0.x + n1.x + n2.x + n3.x;
                    acc.y += n0.y + n1.y + n2.y + n3.y;
                    acc.z += n0.z + n1.z + n2.z + n3.z;
                    acc.w += n0.w + n1.w + n2.w + n3.w;
                } else {
                    const float m0 = (4 * g + 0 < cnt) ? 1.f : 0.f;
                    const float m1 = (4 * g + 1 < cnt) ? 1.f : 0.f;
                    const float m2 = (4 * g + 2 < cnt) ? 1.f : 0.f;
                    const float m3 = (4 * g + 3 < cnt) ? 1.f : 0.f;
                    acc.x += n0.x * m0 + n1.x * m1 + n2.x * m2 + n3.x * m3;
                    acc.y += n0.y * m0 + n1.y * m1 + n2.y * m2 + n3.y * m3;
                    acc.z += n0.z * m0 + n1.z * m1 + n2.z * m2 + n3.z * m3;
                    acc.w += n0.w * m0 + n1.w * m1 + n2.w * m2 + n3.w * m3;
                }
            }
        }
        const float inv = 1.0f / (float)(cnt > 0 ? cnt : 1);
        *(float4*)(&cat_lds[r][D_DIM + col]) =
            make_float4(acc.x * inv, acc.y * inv, acc.z * inv, acc.w * inv);
    }
    __syncthreads();

    // ---- phase 2: t_j = sum_d W[d, j] * v[d]; thread t owns j = 2t, 2t+1 for all 8 rows ----
    const float* vrow[R_BLK];
    #pragma unroll
    for (int r = 0; r < R_BLK; ++r) {
        const int nv = __builtin_amdgcn_readfirstlane(nodes_v[row0 + r]);
        vrow[r] = v2e + (size_t)nv * D_DIM;
    }

    float2 acc2[R_BLK];
    #pragma unroll
    for (int r = 0; r < R_BLK; ++r) acc2[r] = make_float2(0.f, 0.f);

    for (int d = 0; d < D_DIM; d += 4) {
        float4 vq[R_BLK];
        #pragma unroll
        for (int r = 0; r < R_BLK; ++r) vq[r] = *(const float4*)(vrow[r] + d);

        #pragma unroll
        for (int dd = 0; dd < 4; ++dd) {
            const float2 wq = *(const float2*)(W + (size_t)(d + dd) * TWO_D + 2 * t);
            #pragma unroll
            for (int r = 0; r < R_BLK; ++r) {
                const float vs = (dd == 0) ? vq[r].x : (dd == 1) ? vq[r].y
                               : (dd == 2) ? vq[r].z : vq[r].w;
                acc2[r].x += wq.x * vs;
                acc2[r].y += wq.y * vs;
            }
        }
    }

    // ---- epilogue: score = sum_j cat[j] * t_j  (+ b·v), reduce across block ----
    #pragma unroll
    for (int r = 0; r < R_BLK; ++r) {
        const float2 c2 = *(const float2*)(&cat_lds[r][2 * t]);
        float p = c2.x * acc2[r].x + c2.y * acc2[r].y;
        #pragma unroll
        for (int off = 32; off > 0; off >>= 1) p += __shfl_xor(p, off, 64);
        if (lane == 0) red_lds[r * 4 + wave] = p;
    }
    __syncthreads();

    if (t < R_BLK) {
        const int row = row0 + t;
        const int cnt = neighbor_counts[row];
        float s;
        if (cnt > 0) {
            s = red_lds[t * 4 + 0] + red_lds[t * 4 + 1]
              + red_lds[t * 4 + 2] + red_lds[t * 4 + 3] + bdot_lds[t];
        } else {
            s = selfdot_lds[t];
        }
        out[row] = s;
    }
}

extern "C" void kernel_launch(void* const* d_in, const int* in_sizes, int n_in,
                              void* d_out, int out_size, void* d_ws, size_t ws_size,
                              hipStream_t stream) {
    const int*   nodes_u         = (const int*)d_in[0];
    const int*   nodes_v         = (const int*)d_in[1];
    const int*   neighbors       = (const int*)d_in[2];
    const int*   neighbor_counts = (const int*)d_in[3];
    const float* u2e             = (const float*)d_in[4];
    const float* v2e             = (const float*)d_in[5];
    const float* W               = (const float*)d_in[6];
    const float* bias            = (const float*)d_in[7];
    float*       out             = (float*)d_out;

    const int blocks = B_ROWS / R_BLK;   // 2048
    easyrec_fused<<<blocks, THREADS, 0, stream>>>(
        nodes_u, nodes_v, neighbors, neighbor_counts, u2e, v2e, W, bias, out);
}

// Round 6
// 317.671 us; speedup vs baseline: 1.0761x; 1.0761x over previous
//
#include <hip/hip_runtime.h>

#define B_ROWS   16384
#define K_NB     64
#define D_DIM    256
#define TWO_D    512
#define U_ROWS   100000
#define THREADS  256
#define RB       16         // rows per block in fused kernel

#define WS_NEED  ((size_t)U_ROWS * D_DIM * 2)   // 51,200,000 bytes: bf16 u2e copy only

// =================== K1: u2e fp32 -> bf16 (RNE) ===================
__global__ __launch_bounds__(THREADS)
void cvt_bf16_kernel(const float* __restrict__ src, unsigned short* __restrict__ dst)
{
    const int i = blockIdx.x * THREADS + threadIdx.x;       // one float4 per thread
    const uint4 u = ((const uint4*)src)[i];
    ushort4 o;
    o.x = (unsigned short)((u.x + 0x7FFFu + ((u.x >> 16) & 1u)) >> 16);
    o.y = (unsigned short)((u.y + 0x7FFFu + ((u.y >> 16) & 1u)) >> 16);
    o.z = (unsigned short)((u.z + 0x7FFFu + ((u.z >> 16) & 1u)) >> 16);
    o.w = (unsigned short)((u.w + 0x7FFFu + ((u.w >> 16) & 1u)) >> 16);
    ((ushort4*)dst)[i] = o;
}

// bf16 pair -> two fp32 accumulates with mask
__device__ inline void bacc(float4& a, uint2 n, float m)
{
    union { unsigned u; float f; } c0, c1, c2, c3;
    c0.u = n.x << 16; c1.u = n.x & 0xFFFF0000u;
    c2.u = n.y << 16; c3.u = n.y & 0xFFFF0000u;
    a.x += c0.f * m; a.y += c1.f * m; a.z += c2.f * m; a.w += c3.f * m;
}

// =================== K2: fused t=W^T v GEMM + scalars + bf16 gather ===================
// score = self.t1 + (sum_nbr ub).t2 / cnt + b.v   (cnt>0)
//       = self.v                                   (cnt==0)
__global__ __launch_bounds__(THREADS, 4)
void fused_kernel(const int* __restrict__ nodes_u,
                  const int* __restrict__ nodes_v,
                  const int* __restrict__ neighbors,
                  const int* __restrict__ neighbor_counts,
                  const float* __restrict__ u2e,
                  const float* __restrict__ v2e,
                  const float* __restrict__ W,
                  const float* __restrict__ bias,
                  const unsigned short* __restrict__ ub,
                  float* __restrict__ out)
{
    __shared__ __align__(16) float v_lds[RB][D_DIM];     // 16 KB
    __shared__ __align__(16) float t2_lds[RB][D_DIM];    // 16 KB
    __shared__ __align__(16) int   nbr_lds[RB * K_NB];   // 4 KB
    __shared__ int   nu_lds[RB];
    __shared__ float red1[RB][4];                        // partial self.t1 + b.v
    __shared__ float red0[RB][4];                        // partial self.v

    const int t    = threadIdx.x;
    const int wave = t >> 6;
    const int lane = t & 63;
    const int row0 = blockIdx.x * RB;

    // ---- stage: neighbor indices (1024 ints), nodes_u, v rows (16 x 1KB) ----
    #pragma unroll
    for (int i = 0; i < 4; ++i)
        nbr_lds[t + THREADS * i] = neighbors[(size_t)row0 * K_NB + t + THREADS * i];
    if (t < RB) nu_lds[t] = nodes_u[row0 + t];
    #pragma unroll
    for (int rr = 0; rr < 4; ++rr) {
        const int r  = wave + rr * 4;
        const int nv = __builtin_amdgcn_readfirstlane(nodes_v[row0 + r]);
        *(float4*)&v_lds[r][4 * lane] = *(const float4*)(v2e + (size_t)nv * D_DIM + 4 * lane);
    }
    __syncthreads();

    // ---- GEMM: thread t owns j = 2t, 2t+1 of t-vector for all 16 rows ----
    // low register pressure: 4 W-rows (8 regs) held, v streamed per row from LDS (broadcast reads)
    float2 acc2[RB];
    #pragma unroll
    for (int r = 0; r < RB; ++r) acc2[r] = make_float2(0.f, 0.f);

    for (int d = 0; d < D_DIM; d += 4) {
        const float2 wq0 = *(const float2*)(W + (size_t)(d + 0) * TWO_D + 2 * t);
        const float2 wq1 = *(const float2*)(W + (size_t)(d + 1) * TWO_D + 2 * t);
        const float2 wq2 = *(const float2*)(W + (size_t)(d + 2) * TWO_D + 2 * t);
        const float2 wq3 = *(const float2*)(W + (size_t)(d + 3) * TWO_D + 2 * t);
        #pragma unroll
        for (int r = 0; r < RB; ++r) {
            const float4 vv = *(const float4*)&v_lds[r][d];   // wave-uniform broadcast
            acc2[r].x += wq0.x * vv.x + wq1.x * vv.y + wq2.x * vv.z + wq3.x * vv.w;
            acc2[r].y += wq0.y * vv.x + wq1.y * vv.y + wq2.y * vv.z + wq3.y * vv.w;
        }
    }

    // ---- write t2 (j in [256,512)) to LDS; compute per-row scalars ----
    if (t >= 128) {
        const int c = 2 * t - 256;
        #pragma unroll
        for (int r = 0; r < RB; ++r)
            *(float2*)&t2_lds[r][c] = acc2[r];
    }
    for (int r = 0; r < RB; ++r) {
        float p1 = 0.f, p0 = 0.f;
        if (t < 128) {   // acc2[r] here holds (t_{2t}, t_{2t+1}) = t1 components
            const float2 s2  = *(const float2*)(u2e + (size_t)nu_lds[r] * D_DIM + 2 * t);
            const float2 vv2 = *(const float2*)&v_lds[r][2 * t];
            const float2 b2  = *(const float2*)(bias + 2 * t);
            p1 = s2.x * acc2[r].x + s2.y * acc2[r].y + b2.x * vv2.x + b2.y * vv2.y;
            p0 = s2.x * vv2.x + s2.y * vv2.y;
        }
        #pragma unroll
        for (int off = 32; off > 0; off >>= 1) {
            p1 += __shfl_xor(p1, off, 64);
            p0 += __shfl_xor(p0, off, 64);
        }
        if (lane == 0) { red1[r][wave] = p1; red0[r][wave] = p0; }
    }
    __syncthreads();

    // ---- gather: wave w handles rows w, w+4, w+8, w+12; 8-wide unrolled bf16 loads ----
    const int lo = 4 * lane;   // ushort offset within row
    for (int rr = 0; rr < 4; ++rr) {
        const int r   = wave + rr * 4;
        const int row = row0 + r;
        const int cnt = __builtin_amdgcn_readfirstlane(neighbor_counts[row]);

        const float4 t24 = *(const float4*)&t2_lds[r][lo];
        float4 acc = make_float4(0.f, 0.f, 0.f, 0.f);
        const int base = r * K_NB;
        const int kmax = (cnt + 7) & ~7;     // neighbors[] entries are always valid indices

        for (int k = 0; k < kmax; k += 8) {
            const int4 ia = *(const int4*)&nbr_lds[base + k];
            const int4 ib = *(const int4*)&nbr_lds[base + k + 4];
            const int i0 = __builtin_amdgcn_readfirstlane(ia.x);
            const int i1 = __builtin_amdgcn_readfirstlane(ia.y);
            const int i2 = __builtin_amdgcn_readfirstlane(ia.z);
            const int i3 = __builtin_amdgcn_readfirstlane(ia.w);
            const int i4 = __builtin_amdgcn_readfirstlane(ib.x);
            const int i5 = __builtin_amdgcn_readfirstlane(ib.y);
            const int i6 = __builtin_amdgcn_readfirstlane(ib.z);
            const int i7 = __builtin_amdgcn_readfirstlane(ib.w);
            const uint2 n0 = *(const uint2*)(ub + (size_t)i0 * D_DIM + lo);
            const uint2 n1 = *(const uint2*)(ub + (size_t)i1 * D_DIM + lo);
            const uint2 n2 = *(const uint2*)(ub + (size_t)i2 * D_DIM + lo);
            const uint2 n3 = *(const uint2*)(ub + (size_t)i3 * D_DIM + lo);
            const uint2 n4 = *(const uint2*)(ub + (size_t)i4 * D_DIM + lo);
            const uint2 n5 = *(const uint2*)(ub + (size_t)i5 * D_DIM + lo);
            const uint2 n6 = *(const uint2*)(ub + (size_t)i6 * D_DIM + lo);
            const uint2 n7 = *(const uint2*)(ub + (size_t)i7 * D_DIM + lo);
            if (k + 8 <= cnt) {
                bacc(acc, n0, 1.f); bacc(acc, n1, 1.f); bacc(acc, n2, 1.f); bacc(acc, n3, 1.f);
                bacc(acc, n4, 1.f); bacc(acc, n5, 1.f); bacc(acc, n6, 1.f); bacc(acc, n7, 1.f);
            } else {
                bacc(acc, n0, (k + 0 < cnt) ? 1.f : 0.f);
                bacc(acc, n1, (k + 1 < cnt) ? 1.f : 0.f);
                bacc(acc, n2, (k + 2 < cnt) ? 1.f : 0.f);
                bacc(acc, n3, (k + 3 < cnt) ? 1.f : 0.f);
                bacc(acc, n4, (k + 4 < cnt) ? 1.f : 0.f);
                bacc(acc, n5, (k + 5 < cnt) ? 1.f : 0.f);
                bacc(acc, n6, (k + 6 < cnt) ? 1.f : 0.f);
                bacc(acc, n7, (k + 7 < cnt) ? 1.f : 0.f);
            }
        }

        float part = acc.x * t24.x + acc.y * t24.y + acc.z * t24.z + acc.w * t24.w;
        #pragma unroll
        for (int off = 32; off > 0; off >>= 1) part += __shfl_xor(part, off, 64);

        if (lane == 0) {
            const float sb = red1[r][0] + red1[r][1] + red1[r][2] + red1[r][3];
            const float sa = red0[r][0] + red0[r][1] + red0[r][2] + red0[r][3];
            out[row] = (cnt > 0) ? sb + part * (1.0f / (float)cnt) : sa;
        }
    }
}

// =================== fallback: no-ws fused fp32 (R2-proven structure) ===================
#define R_BLK 8
__global__ __launch_bounds__(THREADS)
void easyrec_fused_fb(const int* __restrict__ nodes_u, const int* __restrict__ nodes_v,
                      const int* __restrict__ neighbors, const int* __restrict__ neighbor_counts,
                      const float* __restrict__ u2e, const float* __restrict__ v2e,
                      const float* __restrict__ W, const float* __restrict__ bias,
                      float* __restrict__ out)
{
    __shared__ __align__(16) int nbr_lds[R_BLK * K_NB];
    __shared__ __align__(16) float cat_lds[R_BLK][TWO_D];
    __shared__ float red_lds[R_BLK * 4];
    __shared__ float selfdot_lds[R_BLK];
    __shared__ float bdot_lds[R_BLK];
    const int t = threadIdx.x, wave = t >> 6, lane = t & 63;
    const int row0 = blockIdx.x * R_BLK;
    nbr_lds[t] = neighbors[(size_t)row0 * K_NB + t];
    nbr_lds[t + THREADS] = neighbors[(size_t)row0 * K_NB + t + THREADS];
    __syncthreads();
    for (int rr = 0; rr < 2; ++rr) {
        const int r = wave + rr * 4, row = row0 + r;
        const int nu = __builtin_amdgcn_readfirstlane(nodes_u[row]);
        const int nv = __builtin_amdgcn_readfirstlane(nodes_v[row]);
        const int cnt = __builtin_amdgcn_readfirstlane(neighbor_counts[row]);
        const float4 self4 = *(const float4*)(u2e + (size_t)nu * D_DIM + 4 * lane);
        const float4 v4 = *(const float4*)(v2e + (size_t)nv * D_DIM + 4 * lane);
        const float4 b4 = *(const float4*)(bias + 4 * lane);
        float4 acc = make_float4(0.f, 0.f, 0.f, 0.f);
        const int base = r * K_NB, km = (cnt + 7) & ~7;
        for (int k = 0; k < km; k += 8) {
            const int4 ia = *(const int4*)&nbr_lds[base + k];
            const int4 ib = *(const int4*)&nbr_lds[base + k + 4];
            const float4 n0 = *(const float4*)(u2e + (size_t)ia.x * D_DIM + 4 * lane);
            const float4 n1 = *(const float4*)(u2e + (size_t)ia.y * D_DIM + 4 * lane);
            const float4 n2 = *(const float4*)(u2e + (size_t)ia.z * D_DIM + 4 * lane);
            const float4 n3 = *(const float4*)(u2e + (size_t)ia.w * D_DIM + 4 * lane);
            const float4 n4 = *(const float4*)(u2e + (size_t)ib.x * D_DIM + 4 * lane);
            const float4 n5 = *(const float4*)(u2e + (size_t)ib.y * D_DIM + 4 * lane);
            const float4 n6 = *(const float4*)(u2e + (size_t)ib.z * D_DIM + 4 * lane);
            const float4 n7 = *(const float4*)(u2e + (size_t)ib.w * D_DIM + 4 * lane);
            const float m0 = (k+0<cnt)?1.f:0.f, m1=(k+1<cnt)?1.f:0.f, m2=(k+2<cnt)?1.f:0.f, m3=(k+3<cnt)?1.f:0.f;
            const float m4 = (k+4<cnt)?1.f:0.f, m5=(k+5<cnt)?1.f:0.f, m6=(k+6<cnt)?1.f:0.f, m7=(k+7<cnt)?1.f:0.f;
            acc.x += n0.x*m0+n1.x*m1+n2.x*m2+n3.x*m3+n4.x*m4+n5.x*m5+n6.x*m6+n7.x*m7;
            acc.y += n0.y*m0+n1.y*m1+n2.y*m2+n3.y*m3+n4.y*m4+n5.y*m5+n6.y*m6+n7.y*m7;
            acc.z += n0.z*m0+n1.z*m1+n2.z*m2+n3.z*m3+n4.z*m4+n5.z*m5+n6.z*m6+n7.z*m7;
            acc.w += n0.w*m0+n1.w*m1+n2.w*m2+n3.w*m3+n4.w*m4+n5.w*m5+n6.w*m6+n7.w*m7;
        }
        const float inv = 1.0f / (float)(cnt > 0 ? cnt : 1);
        *(float4*)(&cat_lds[r][4 * lane]) = self4;
        *(float4*)(&cat_lds[r][D_DIM + 4 * lane]) = make_float4(acc.x*inv, acc.y*inv, acc.z*inv, acc.w*inv);
        float sv = self4.x*v4.x + self4.y*v4.y + self4.z*v4.z + self4.w*v4.w;
        float bv = b4.x*v4.x + b4.y*v4.y + b4.z*v4.z + b4.w*v4.w;
        #pragma unroll
        for (int off = 32; off > 0; off >>= 1) { sv += __shfl_xor(sv, off, 64); bv += __shfl_xor(bv, off, 64); }
        if (lane == 0) { selfdot_lds[r] = sv; bdot_lds[r] = bv; }
    }
    __syncthreads();
    const float* vrow[R_BLK];
    #pragma unroll
    for (int r = 0; r < R_BLK; ++r)
        vrow[r] = v2e + (size_t)__builtin_amdgcn_readfirstlane(nodes_v[row0 + r]) * D_DIM;
    float2 acc2[R_BLK];
    #pragma unroll
    for (int r = 0; r < R_BLK; ++r) acc2[r] = make_float2(0.f, 0.f);
    for (int d = 0; d < D_DIM; d += 4) {
        float4 vq[R_BLK];
        #pragma unroll
        for (int r = 0; r < R_BLK; ++r) vq[r] = *(const float4*)(vrow[r] + d);
        #pragma unroll
        for (int dd = 0; dd < 4; ++dd) {
            const float2 wq = *(const float2*)(W + (size_t)(d + dd) * TWO_D + 2 * t);
            #pragma unroll
            for (int r = 0; r < R_BLK; ++r) {
                const float vs = (dd==0)?vq[r].x:(dd==1)?vq[r].y:(dd==2)?vq[r].z:vq[r].w;
                acc2[r].x += wq.x * vs; acc2[r].y += wq.y * vs;
            }
        }
    }
    #pragma unroll
    for (int r = 0; r < R_BLK; ++r) {
        const float2 c2 = *(const float2*)(&cat_lds[r][2 * t]);
        float p = c2.x * acc2[r].x + c2.y * acc2[r].y;
        #pragma unroll
        for (int off = 32; off > 0; off >>= 1) p += __shfl_xor(p, off, 64);
        if (lane == 0) red_lds[r * 4 + wave] = p;
    }
    __syncthreads();
    if (t < R_BLK) {
        const int row = row0 + t, cnt = neighbor_counts[row];
        out[row] = (cnt > 0)
            ? red_lds[t*4+0] + red_lds[t*4+1] + red_lds[t*4+2] + red_lds[t*4+3] + bdot_lds[t]
            : selfdot_lds[t];
    }
}

extern "C" void kernel_launch(void* const* d_in, const int* in_sizes, int n_in,
                              void* d_out, int out_size, void* d_ws, size_t ws_size,
                              hipStream_t stream) {
    const int*   nodes_u         = (const int*)d_in[0];
    const int*   nodes_v         = (const int*)d_in[1];
    const int*   neighbors       = (const int*)d_in[2];
    const int*   neighbor_counts = (const int*)d_in[3];
    const float* u2e             = (const float*)d_in[4];
    const float* v2e             = (const float*)d_in[5];
    const float* W               = (const float*)d_in[6];
    const float* bias            = (const float*)d_in[7];
    float*       out             = (float*)d_out;

    if (ws_size < WS_NEED) {
        easyrec_fused_fb<<<B_ROWS / R_BLK, THREADS, 0, stream>>>(
            nodes_u, nodes_v, neighbors, neighbor_counts, u2e, v2e, W, bias, out);
        return;
    }

    unsigned short* ub = (unsigned short*)d_ws;
    cvt_bf16_kernel<<<U_ROWS * D_DIM / 4 / THREADS, THREADS, 0, stream>>>(u2e, ub);
    fused_kernel<<<B_ROWS / RB, THREADS, 0, stream>>>(
        nodes_u, nodes_v, neighbors, neighbor_counts, u2e, v2e, W, bias, ub, out);
}